// Round 2
// baseline (317.256 us; speedup 1.0000x reference)
//
#include <hip/hip_runtime.h>

// Water constraint residuals:
//   x: [B=16, N=200000, D=18] fp32; positions = x[..., :9] as [3 particles][xyz]
//   dr0 = r0-r1, dr1 = r1-r2, dr2 = r2-r0 ; c_k = |dr_k| - l_k -> out [B, N, 3] fp32
//
// Round 2: dead-simple version. No LDS, no cross-type aliasing, no syncthreads.
// One thread per molecule. Record stride = 72 B => 8B-aligned float2 loads are
// always legal. Wave reads a contiguous 4.6 KB span, writes contiguous 768 B.

constexpr int F_PER_MOL = 18;   // 9 pos + 9 vel floats
constexpr int BLOCK = 256;

__global__ __launch_bounds__(BLOCK) void water_kernel(
    const float* __restrict__ x,
    const float* __restrict__ l,
    float* __restrict__ out,
    long long total_mol)
{
    const long long mol = (long long)blockIdx.x * BLOCK + threadIdx.x;
    if (mol >= total_mol) return;

    const float* __restrict__ m = x + mol * F_PER_MOL;
    // 72*mol bytes is 8B-aligned -> float2 loads are safe.
    const float2 p01 = *reinterpret_cast<const float2*>(m + 0);  // r0.x r0.y
    const float2 p23 = *reinterpret_cast<const float2*>(m + 2);  // r0.z r1.x
    const float2 p45 = *reinterpret_cast<const float2*>(m + 4);  // r1.y r1.z
    const float2 p67 = *reinterpret_cast<const float2*>(m + 6);  // r2.x r2.y
    const float  p8  = m[8];                                     // r2.z

    const float ox = p01.x, oy = p01.y, oz = p23.x;
    const float ax = p23.y, ay = p45.x, az = p45.y;
    const float bx = p67.x, by = p67.y, bz = p8;

    const float d0x = ox - ax, d0y = oy - ay, d0z = oz - az;   // r0 - r1
    const float d1x = ax - bx, d1y = ay - by, d1z = az - bz;   // r1 - r2
    const float d2x = bx - ox, d2y = by - oy, d2z = bz - oz;   // r2 - r0

    const float n0 = sqrtf(d0x * d0x + d0y * d0y + d0z * d0z);
    const float n1 = sqrtf(d1x * d1x + d1y * d1y + d1z * d1z);
    const float n2 = sqrtf(d2x * d2x + d2y * d2y + d2z * d2z);

    // l pointer is wave-uniform -> compiler emits scalar loads.
    const float l0 = l[0], l1 = l[1], l2 = l[2];

    float* o = out + mol * 3;
    o[0] = n0 - l0;
    o[1] = n1 - l1;
    o[2] = n2 - l2;
}

extern "C" void kernel_launch(void* const* d_in, const int* in_sizes, int n_in,
                              void* d_out, int out_size, void* d_ws, size_t ws_size,
                              hipStream_t stream)
{
    const float* x = (const float*)d_in[0];   // [B*N*18] fp32
    const float* l = (const float*)d_in[1];   // [3] fp32
    float* out = (float*)d_out;               // [B*N*3] fp32

    const long long total_mol = (long long)in_sizes[0] / F_PER_MOL;  // 3,200,000
    const int grid = (int)((total_mol + BLOCK - 1) / BLOCK);

    water_kernel<<<grid, BLOCK, 0, stream>>>(x, l, out, total_mol);
}